// Round 5
// baseline (860.840 us; speedup 1.0000x reference)
//
#include <hip/hip_runtime.h>
#include <hip/hip_bf16.h>

#define E_EDGES 262144
#define N_NODES 16384

typedef short bf16x8 __attribute__((ext_vector_type(8)));
typedef float f32x4 __attribute__((ext_vector_type(4)));

static __device__ __forceinline__ short f2bf(float f) {
    union { float f; unsigned u; } v; v.f = f;
    unsigned r = v.u + 0x7FFFu + ((v.u >> 16) & 1u);
    return (short)(r >> 16);
}
static __device__ __forceinline__ float bf2f(short s) {
    union { unsigned u; float f; } v;
    v.u = ((unsigned)(unsigned short)s) << 16;
    return v.f;
}

// ---------------- weight prep: bf16 transposed copies ----------------
// WenvT[c*128+k] = W_env[k*64+c]             (64 x 128)
// WcatT[c*96+k]  = [W_mix | W_sc][k][c]      (256 x 96, k>=80 zero)
// WkB[m][c][dp]  = dp<16 ? Wk[c*512+m*16+dp] : 0   (32 x 128 x 32, K-padded)
__global__ void kprep(const float* __restrict__ Wk, const float* __restrict__ Wenv,
                      const float* __restrict__ Wmix, const float* __restrict__ Wsc,
                      short* __restrict__ WenvT, short* __restrict__ WcatT,
                      short* __restrict__ WkB) {
    int idx = blockIdx.x * 256 + threadIdx.x;
    if (idx < 8192) {
        int c = idx >> 7, k = idx & 127;
        WenvT[idx] = f2bf(Wenv[k * 64 + c]);
    } else if (idx < 8192 + 24576) {
        int o = idx - 8192;
        int c = o / 96, k = o - c * 96;
        float v = 0.f;
        if (k < 80) v = (c < 128) ? Wmix[k * 128 + c] : Wsc[k * 128 + (c - 128)];
        WcatT[o] = f2bf(v);
    } else {
        int o = idx - 32768;
        int m = o >> 12, rest = o & 4095;
        int c = rest >> 5, dp = rest & 31;
        WkB[o] = (dp < 16) ? f2bf(Wk[c * 512 + m * 16 + dp]) : (short)0;
    }
}

// ---------------- CSR build: histogram, scan, scatter ----------------
__global__ void khist(const int* __restrict__ ec, int* __restrict__ deg) {
    int e = blockIdx.x * 256 + threadIdx.x;
    atomicAdd(&deg[ec[e]], 1);
}

__global__ void kscan(const int* __restrict__ deg, int* __restrict__ offs,
                      int* __restrict__ cursor) {
    __shared__ int part[256];
    int t = threadIdx.x;
    int s = 0;
    for (int i = 0; i < 64; ++i) s += deg[t * 64 + i];
    part[t] = s;
    __syncthreads();
    if (t == 0) {
        int acc = 0;
        for (int i = 0; i < 256; ++i) { int v = part[i]; part[i] = acc; acc += v; }
        offs[N_NODES] = acc;
    }
    __syncthreads();
    int p = part[t];
    for (int i = 0; i < 64; ++i) {
        int idx = t * 64 + i;
        offs[idx] = p;
        cursor[idx] = p;
        p += deg[idx];
    }
}

__global__ void kscat(const int* __restrict__ ec, int* __restrict__ cursor,
                      int* __restrict__ csr) {
    int e = blockIdx.x * 256 + threadIdx.x;
    int p = atomicAdd(&cursor[ec[e]], 1);
    csr[p] = e;
}

// ---------------- Qn = node_invariants @ Wq  (N x 512, fp32) ----------------
__global__ void kqn(const float* __restrict__ ninv, const float* __restrict__ Wq,
                    float* __restrict__ Qn) {
    __shared__ float ni[8 * 68];
    int nBase = blockIdx.x * 8;
    int tid = threadIdx.x;
    for (int idx = tid; idx < 512; idx += 256) {
        int n = idx >> 6, j = idx & 63;
        ni[n * 68 + j] = ninv[(nBase + n) * 64 + j];
    }
    __syncthreads();
    float a0[8] = {0,0,0,0,0,0,0,0};
    float a1[8] = {0,0,0,0,0,0,0,0};
    for (int j = 0; j < 64; ++j) {
        float w0 = Wq[j * 512 + tid];
        float w1 = Wq[j * 512 + tid + 256];
#pragma unroll
        for (int n = 0; n < 8; ++n) {
            float s = ni[n * 68 + j];
            a0[n] += s * w0;
            a1[n] += s * w1;
        }
    }
#pragma unroll
    for (int n = 0; n < 8; ++n) {
        Qn[(nBase + n) * 512 + tid] = a0[n];
        Qn[(nBase + n) * 512 + tid + 256] = a1[n];
    }
}

// ---------------- kV: VT[nloc][m][c] = bf16( sum_d Wk[c,m*16+d] * Q[n,m*16+d] ) ----
__launch_bounds__(256)
__global__ void kV(const float* __restrict__ Qn, const short* __restrict__ WkB,
                   short* __restrict__ VT, int nb0) {
    int tid = threadIdx.x;
    int w = tid >> 6, lane = tid & 63;
    int r = lane & 15, q = lane >> 4;
    int nbl = blockIdx.x * 16;
#pragma unroll
    for (int mi = 0; mi < 8; ++mi) {
        int m = w * 8 + mi;
        const float* qp = &Qn[(size_t)(nb0 + nbl + r) * 512 + m * 16 + (q & 1) * 8];
        float4 qa = *(const float4*)qp;
        float4 qb = *(const float4*)(qp + 4);
        bf16x8 af;
        af[0] = f2bf(qa.x); af[1] = f2bf(qa.y); af[2] = f2bf(qa.z); af[3] = f2bf(qa.w);
        af[4] = f2bf(qb.x); af[5] = f2bf(qb.y); af[6] = f2bf(qb.z); af[7] = f2bf(qb.w);
#pragma unroll
        for (int ct = 0; ct < 8; ++ct) {
            bf16x8 bb = *(const bf16x8*)&WkB[(m * 128 + ct * 16 + r) * 32 + q * 8];
            f32x4 acc = {0.f, 0.f, 0.f, 0.f};
            acc = __builtin_amdgcn_mfma_f32_16x16x32_bf16(af, bb, acc, 0, 0, 0);
#pragma unroll
            for (int reg = 0; reg < 4; ++reg) {
                VT[(size_t)(nbl + q * 4 + reg) * 4096 + m * 128 + ct * 16 + r] =
                    f2bf(acc[reg]);
            }
        }
    }
}

// ---------------- kmain2: per-node fused logits/g/attn-aggregate/LN ----------------
__launch_bounds__(256)
__global__ void kmain2(const float* __restrict__ sl, const float* __restrict__ equiv,
                       const int* __restrict__ csr, const int* __restrict__ offs,
                       const short* __restrict__ VT, const short* __restrict__ WenvT,
                       const float* __restrict__ benv, float* __restrict__ envn,
                       int nb0) {
    __shared__ short slb[4][16 * 136];
    __shared__ short glds[4][16 * 68];
    int tid = threadIdx.x;
    int w = tid >> 6, lane = tid & 63;
    int r = lane & 15, q = lane >> 4;
    int node = nb0 + blockIdx.x * 4 + w;
    int start = offs[node], end = offs[node + 1];
    if (start >= end) return;   // no barriers in this kernel -> per-wave return is safe

    bf16x8 vb[2][4];
    const short* vtn = VT + (size_t)(node - nb0) * 4096;
#pragma unroll
    for (int ct = 0; ct < 2; ++ct)
#pragma unroll
        for (int kk = 0; kk < 4; ++kk)
            vb[ct][kk] = *(const bf16x8*)&vtn[(ct * 16 + r) * 128 + kk * 32 + q * 8];
    float bias[4];
#pragma unroll
    for (int g4 = 0; g4 < 4; ++g4) bias[g4] = benv[g4 * 16 + r];

    float facc[2][4] = {{0,0,0,0},{0,0,0,0}};
    float dsum[2] = {0.f, 0.f};

    for (int c0 = start; c0 < end; c0 += 16) {
        int cnt = end - c0; if (cnt > 16) cnt = 16;
#pragma unroll
        for (int i = 0; i < 8; ++i) {
            int idx4 = i * 64 + lane;
            int e = idx4 >> 5, j4 = idx4 & 31;
            float4 v = {0.f, 0.f, 0.f, 0.f};
            if (e < cnt) {
                int ge = csr[c0 + e];
                v = *(const float4*)&sl[(size_t)ge * 128 + j4 * 4];
            }
            short4 s4; s4.x = f2bf(v.x); s4.y = f2bf(v.y); s4.z = f2bf(v.z); s4.w = f2bf(v.w);
            *(short4*)&slb[w][e * 136 + j4 * 4] = s4;
        }
        asm volatile("s_waitcnt lgkmcnt(0)" ::: "memory");
        bf16x8 af[4];
#pragma unroll
        for (int kk = 0; kk < 4; ++kk)
            af[kk] = *(const bf16x8*)&slb[w][r * 136 + kk * 32 + q * 8];

        float zv[2][4];
#pragma unroll
        for (int ct = 0; ct < 2; ++ct) {
            f32x4 acc = {0.f, 0.f, 0.f, 0.f};
#pragma unroll
            for (int kk = 0; kk < 4; ++kk)
                acc = __builtin_amdgcn_mfma_f32_16x16x32_bf16(af[kk], vb[ct][kk], acc, 0, 0, 0);
#pragma unroll
            for (int reg = 0; reg < 4; ++reg) {
                float l = acc[reg] * 0.25f;            // INV_SQRTD
                l = fminf(5.f, fmaxf(-5.f, l));        // clip
                zv[ct][reg] = __expf(l);
            }
        }

#pragma unroll
        for (int g4 = 0; g4 < 4; ++g4) {
            f32x4 acc = {0.f, 0.f, 0.f, 0.f};
#pragma unroll
            for (int kk = 0; kk < 4; ++kk) {
                bf16x8 bb = *(const bf16x8*)&WenvT[(g4 * 16 + r) * 128 + kk * 32 + q * 8];
                acc = __builtin_amdgcn_mfma_f32_16x16x32_bf16(af[kk], bb, acc, 0, 0, 0);
            }
#pragma unroll
            for (int reg = 0; reg < 4; ++reg) {
                float x = acc[reg] + bias[g4];
                float gv = x / (1.f + __expf(-x));
                glds[w][(q * 4 + reg) * 68 + g4 * 16 + r] = f2bf(gv);
            }
        }
        asm volatile("s_waitcnt lgkmcnt(0)" ::: "memory");

#pragma unroll
        for (int reg = 0; reg < 4; ++reg) {
            int e = q * 4 + reg;
            if (e < cnt) {
                int ge = csr[c0 + e];
#pragma unroll
                for (int ct = 0; ct < 2; ++ct) {
                    int m = ct * 16 + r;
                    float z = zv[ct][reg];
                    unsigned gp = *(const unsigned*)&glds[w][e * 68 + 2 * m];
                    float g0 = bf2f((short)(gp & 0xFFFFu));
                    float g1 = bf2f((short)(gp >> 16));
                    float4 eq = *(const float4*)&equiv[(size_t)ge * 128 + m * 4];
                    facc[ct][0] += z * g0 * eq.x;
                    facc[ct][1] += z * g1 * eq.y;
                    facc[ct][2] += z * g1 * eq.z;
                    facc[ct][3] += z * g1 * eq.w;
                    dsum[ct] += z;
                }
            }
        }
    }

#pragma unroll
    for (int off = 16; off < 64; off <<= 1) {
#pragma unroll
        for (int ct = 0; ct < 2; ++ct) {
#pragma unroll
            for (int i = 0; i < 4; ++i) facc[ct][i] += __shfl_xor(facc[ct][i], off, 64);
            dsum[ct] += __shfl_xor(dsum[ct], off, 64);
        }
    }
    float env0[4], env1[4];
    float inv0 = 1.f / dsum[0], inv1 = 1.f / dsum[1];
#pragma unroll
    for (int i = 0; i < 4; ++i) { env0[i] = facc[0][i] * inv0; env1[i] = facc[1][i] * inv1; }
    float p0 = env0[0] * env0[0] + env1[0] * env1[0];
    float p1 = env0[1]*env0[1] + env0[2]*env0[2] + env0[3]*env0[3]
             + env1[1]*env1[1] + env1[2]*env1[2] + env1[3]*env1[3];
#pragma unroll
    for (int off = 1; off < 16; off <<= 1) {
        p0 += __shfl_xor(p0, off, 64);
        p1 += __shfl_xor(p1, off, 64);
    }
    float i0 = rsqrtf(p0 * (1.f / 32.f) + 1e-6f);
    float i1 = rsqrtf(p1 * (1.f / 96.f) + 1e-6f);
    if (q == 0) {
        float4 o0, o1;
        o0.x = env0[0] * i0; o0.y = env0[1] * i1; o0.z = env0[2] * i1; o0.w = env0[3] * i1;
        o1.x = env1[0] * i0; o1.y = env1[1] * i1; o1.z = env1[2] * i1; o1.w = env1[3] * i1;
        *(float4*)&envn[(size_t)node * 128 + r * 4] = o0;
        *(float4*)&envn[(size_t)node * 128 + 64 + r * 4] = o1;
    }
}

// ---------------- final: tp + LN, swapped-operand GEMM, reg-handoff outputs ----------------
// mfma(A=WcatT, B=feats): C col = edge (lane&15), C rows = 4 consecutive out-channels
// (q*4+reg) -> the thread that computes mix[e][m*4..m*4+3] also computes new_equiv.
// mixl LDS + second barrier eliminated; scalar half writes float4 with prefetched sl.
__launch_bounds__(256)
__global__ void kfinal(const float* __restrict__ sl, const float* __restrict__ equiv,
                       const float* __restrict__ econd, const int* __restrict__ ec,
                       const float* __restrict__ envn, const short* __restrict__ WcatT,
                       const float* __restrict__ bmix, const float* __restrict__ bsc,
                       const float* __restrict__ ucp, float* __restrict__ out) {
    __shared__ short featb[16 * 104];   // [e][k]: tp0n(32) tp7n(32) cond(16) 0(16) pad(8)
    __shared__ float tpl[16 * 194];     // [e][(c-1)*32 + m], c = 1..6, normalized f32

    int tid = threadIdx.x;
    int eBase = blockIdx.x * 16;
    int lane = tid & 63, wv = tid >> 6;
    int r = lane & 15, q = lane >> 4;
    int e = tid >> 4, i = tid & 15;
    int ge = eBase + e;

    float uc = ucp[0];
    float c_old = rsqrtf(uc * uc + 1.f);
    float c_new = uc * c_old;

    // prefetch sl residual rows for the scalar half (waves 2,3); addresses static
    float4 slp[4];
    if (wv >= 2) {
#pragma unroll
        for (int ct4 = 0; ct4 < 4; ++ct4) {
            int j0 = (wv * 4 + ct4 - 8) * 16 + q * 4;
            slp[ct4] = *(const float4*)&sl[(size_t)(eBase + r) * 128 + j0];
        }
    }

    // direct loads in consuming layout
    int cnode = ec[ge];
    float4 x0 = *(const float4*)&equiv[(size_t)ge * 128 + (i * 2) * 4];
    float4 x1 = *(const float4*)&equiv[(size_t)ge * 128 + (i * 2 + 1) * 4];
    float4 y0 = *(const float4*)&envn[(size_t)cnode * 128 + (i * 2) * 4];
    float4 y1 = *(const float4*)&envn[(size_t)cnode * 128 + (i * 2 + 1) * 4];
    float cond = econd[(size_t)eBase * 16 + tid];

    // ---- phase 1: tensor product + per-edge SO3 LN -> featb + tpl ----
    {
        float tp[2][8];
        float s0, s1, s2, s3;
        tp[0][0] = x0.x * y0.x;
        tp[0][1] = x0.x * y0.y; tp[0][2] = x0.x * y0.z; tp[0][3] = x0.x * y0.w;
        tp[0][4] = x0.y * y0.x; tp[0][5] = x0.z * y0.x; tp[0][6] = x0.w * y0.x;
        tp[0][7] = (x0.y * y0.y + x0.z * y0.z + x0.w * y0.w) * 0.57735026919f;
        tp[1][0] = x1.x * y1.x;
        tp[1][1] = x1.x * y1.y; tp[1][2] = x1.x * y1.z; tp[1][3] = x1.x * y1.w;
        tp[1][4] = x1.y * y1.x; tp[1][5] = x1.z * y1.x; tp[1][6] = x1.w * y1.x;
        tp[1][7] = (x1.y * y1.y + x1.z * y1.z + x1.w * y1.w) * 0.57735026919f;
        s0 = tp[0][0] * tp[0][0] + tp[1][0] * tp[1][0];
        s1 = tp[0][1] * tp[0][1] + tp[0][2] * tp[0][2] + tp[0][3] * tp[0][3]
           + tp[1][1] * tp[1][1] + tp[1][2] * tp[1][2] + tp[1][3] * tp[1][3];
        s2 = tp[0][4] * tp[0][4] + tp[0][5] * tp[0][5] + tp[0][6] * tp[0][6]
           + tp[1][4] * tp[1][4] + tp[1][5] * tp[1][5] + tp[1][6] * tp[1][6];
        s3 = tp[0][7] * tp[0][7] + tp[1][7] * tp[1][7];
#pragma unroll
        for (int off = 1; off < 16; off <<= 1) {
            s0 += __shfl_xor(s0, off, 16);
            s1 += __shfl_xor(s1, off, 16);
            s2 += __shfl_xor(s2, off, 16);
            s3 += __shfl_xor(s3, off, 16);
        }
        float i0 = rsqrtf(s0 * (1.f / 32.f) + 1e-6f);
        float i1 = rsqrtf(s1 * (1.f / 96.f) + 1e-6f);
        float i2 = rsqrtf(s2 * (1.f / 96.f) + 1e-6f);
        float i3 = rsqrtf(s3 * (1.f / 32.f) + 1e-6f);
#pragma unroll
        for (int t2 = 0; t2 < 2; ++t2) {
            int m = i * 2 + t2;
            featb[e * 104 + m]      = f2bf(tp[t2][0] * i0);
            featb[e * 104 + 32 + m] = f2bf(tp[t2][7] * i3);
            tpl[e * 194 +       m] = tp[t2][1] * i1;
            tpl[e * 194 +  32 + m] = tp[t2][2] * i1;
            tpl[e * 194 +  64 + m] = tp[t2][3] * i1;
            tpl[e * 194 +  96 + m] = tp[t2][4] * i2;
            tpl[e * 194 + 128 + m] = tp[t2][5] * i2;
            tpl[e * 194 + 160 + m] = tp[t2][6] * i2;
        }
        featb[e * 104 + 64 + i] = f2bf(cond);
        featb[e * 104 + 80 + i] = 0;
    }
    __syncthreads();

    // ---- phase 2: swapped-operand MFMA. A=WcatT (cols of output), B=feats (edges) ----
    f32x4 macc[4];
    {
        bf16x8 bfeat[3];
#pragma unroll
        for (int kk = 0; kk < 3; ++kk)
            bfeat[kk] = *(const bf16x8*)&featb[r * 104 + kk * 32 + q * 8];
#pragma unroll
        for (int ct4 = 0; ct4 < 4; ++ct4) {
            int ct = wv * 4 + ct4;
            f32x4 acc = {0.f, 0.f, 0.f, 0.f};
#pragma unroll
            for (int kk = 0; kk < 3; ++kk) {
                bf16x8 aw = *(const bf16x8*)&WcatT[(ct * 16 + r) * 96 + kk * 32 + q * 8];
                acc = __builtin_amdgcn_mfma_f32_16x16x32_bf16(aw, bfeat[kk], acc, 0, 0, 0);
            }
            if (wv < 2) {
                // mix half: acc = mix[e=r][colg = ct*16+q*4+reg], add bias, keep in regs
                float4 bm = *(const float4*)&bmix[ct * 16 + q * 4];
                acc[0] += bm.x; acc[1] += bm.y; acc[2] += bm.z; acc[3] += bm.w;
                macc[ct4] = acc;
            } else {
                // scalar half: float4 out write with prefetched sl residual
                int j0 = (ct - 8) * 16 + q * 4;
                float4 bs = *(const float4*)&bsc[j0];
                float4 o;
                o.x = c_old * slp[ct4].x + c_new * (acc[0] + bs.x);
                o.y = c_old * slp[ct4].y + c_new * (acc[1] + bs.y);
                o.z = c_old * slp[ct4].z + c_new * (acc[2] + bs.z);
                o.w = c_old * slp[ct4].w + c_new * (acc[3] + bs.w);
                *(float4*)&out[(size_t)(eBase + r) * 128 + j0] = o;
            }
        }
    }

    // ---- phase 3 (waves 0,1): new_equiv + residual, mix held in registers ----
    if (wv < 2) {
        float* outeq = out + (size_t)E_EDGES * 128;
#pragma unroll
        for (int ct4 = 0; ct4 < 4; ++ct4) {
            int m = (wv * 4 + ct4) * 4 + q;
            float4 x = *(const float4*)&equiv[(size_t)(eBase + r) * 128 + m * 4];
            float tp0n = bf2f(featb[r * 104 + m]);
            float tp7n = bf2f(featb[r * 104 + 32 + m]);
            float t1 = tpl[r * 194 +       m];
            float t2 = tpl[r * 194 +  32 + m];
            float t3 = tpl[r * 194 +  64 + m];
            float t4 = tpl[r * 194 +  96 + m];
            float t5 = tpl[r * 194 + 128 + m];
            float t6 = tpl[r * 194 + 160 + m];
            f32x4 mx = macc[ct4];
            float4 o;
            o.x = c_old * x.x + c_new * (mx[0] * tp0n + mx[1] * tp7n);
            o.y = c_old * x.y + c_new * (mx[2] * t1 + mx[3] * t4);
            o.z = c_old * x.z + c_new * (mx[2] * t2 + mx[3] * t5);
            o.w = c_old * x.w + c_new * (mx[2] * t3 + mx[3] * t6);
            *(float4*)&outeq[(size_t)(eBase + r) * 128 + m * 4] = o;
        }
    }
}

extern "C" void kernel_launch(void* const* d_in, const int* in_sizes, int n_in,
                              void* d_out, int out_size, void* d_ws, size_t ws_size,
                              hipStream_t stream) {
    const float* sl    = (const float*)d_in[0];
    const float* eqv   = (const float*)d_in[1];
    const float* ninv  = (const float*)d_in[2];
    const float* econd = (const float*)d_in[3];
    const float* uc    = (const float*)d_in[4];
    const float* Wenv  = (const float*)d_in[5];
    const float* benv  = (const float*)d_in[6];
    const float* Wq    = (const float*)d_in[7];
    const float* Wk    = (const float*)d_in[8];
    const float* Wmix  = (const float*)d_in[9];
    const float* bmix  = (const float*)d_in[10];
    const float* Wsc   = (const float*)d_in[11];
    const float* bsc   = (const float*)d_in[12];
    const int*   ec    = (const int*)d_in[13];
    float* out = (float*)d_out;

    const int NHALF = N_NODES / 2;   // VT double-pass to stay in ws budget

    float* ws = (float*)d_ws;
    float* Qn    = ws;                                     // N*512 f32
    float* envn  = Qn + (size_t)N_NODES * 512;             // N*128 f32
    short* VT    = (short*)(envn + (size_t)N_NODES * 128); // NHALF*4096 bf16
    short* WenvT = VT + (size_t)NHALF * 4096;              // 64*128
    short* WcatT = WenvT + 8192;                           // 256*96
    short* WkB   = WcatT + 24576;                          // 32*128*32
    int*   deg    = (int*)(WkB + 131072);                  // N
    int*   offs   = deg + N_NODES;                         // N+1
    int*   cursor = offs + N_NODES + 1;                    // N
    int*   csr    = cursor + N_NODES;                      // E

    hipMemsetAsync(deg, 0, (size_t)N_NODES * sizeof(int), stream);
    hipMemsetAsync(envn, 0, (size_t)N_NODES * 128 * sizeof(float), stream);

    kprep<<<640, 256, 0, stream>>>(Wk, Wenv, Wmix, Wsc, WenvT, WcatT, WkB);
    khist<<<E_EDGES / 256, 256, 0, stream>>>(ec, deg);
    kscan<<<1, 256, 0, stream>>>(deg, offs, cursor);
    kscat<<<E_EDGES / 256, 256, 0, stream>>>(ec, cursor, csr);
    kqn<<<N_NODES / 8, 256, 0, stream>>>(ninv, Wq, Qn);

    for (int pass = 0; pass < 2; ++pass) {
        int nb0 = pass * NHALF;
        kV<<<NHALF / 16, 256, 0, stream>>>(Qn, WkB, VT, nb0);
        kmain2<<<NHALF / 4, 256, 0, stream>>>(sl, eqv, csr, offs, VT, WenvT, benv, envn, nb0);
    }

    kfinal<<<E_EDGES / 16, 256, 0, stream>>>(sl, eqv, econd, ec, envn, WcatT, bmix, bsc, uc, out);
}